// Round 7
// baseline (1074.147 us; speedup 1.0000x reference)
//
#include <hip/hip_runtime.h>
#include <math.h>

typedef __attribute__((ext_vector_type(8))) short short8;
typedef __attribute__((ext_vector_type(4))) float floatx4;

#define M_TOT 200704            // 64*56*56 token rows
#define SCALE_Q 0.17677669529663687f   // 32^-0.5

__device__ __forceinline__ float u2f(unsigned int u){ return __uint_as_float(u << 16); }
__device__ __forceinline__ unsigned short f2u(float f){
  unsigned int x = __float_as_uint(f);
  x += 0x7fffu + ((x >> 16) & 1u);       // RNE f32->bf16
  return (unsigned short)(x >> 16);
}

// async global->LDS, 16B per lane; LDS dest is wave-uniform base + lane*16
#define GLD16(gp, lp) __builtin_amdgcn_global_load_lds( \
    (const __attribute__((address_space(1))) void*)(gp), \
    (__attribute__((address_space(3))) void*)(lp), 16, 0, 0)

// 16B-granule swizzle for 64B rows (4 granules): involution, both-sides.
// b128 reads across 16 consecutive rows land <=2 lanes per bank group (free).
__device__ __forceinline__ int sw32(int r, int g){ return g ^ ((r ^ (r >> 2)) & 3); }

// window-layout row m -> spatial row of x (shift+partition gather; same map is the
// reverse+unshift scatter destination: both are +3 cyclic in each axis)
__device__ __forceinline__ int win_to_x(int m){
  int bb = m / 3136; int rem = m - bb*3136;
  int w = rem / 49, n = rem - w*49;
  int wh = w >> 3, ww = w & 7;
  int i = n / 7, j = n - i*7;
  int p = wh*7 + i + 3; if (p >= 56) p -= 56;
  int q = ww*7 + j + 3; if (q >= 56) q -= 56;
  return bb*3136 + p*56 + q;
}

// ---------------- prep: f32 W[K][N] -> bf16 Wt[N][K] ----------------
__global__ void conv_wt(const float* __restrict__ in, unsigned short* __restrict__ out,
                        int K, int N){
  int t = blockIdx.x*256 + threadIdx.x;
  if (t < K*N){ int n = t / K, k = t - n*K; out[t] = f2u(in[k*N + n]); }
}
// ---------------- prep: row gather/scatter map ----------------
__global__ void rowmap_k(int* __restrict__ map){
  int t = blockIdx.x*256 + threadIdx.x;
  if (t < M_TOT) map[t] = win_to_x(t);
}
// ---------------- prep: bias+mask table BM[w][h][i][j] bf16, 64x64 padded ----
__global__ void bm_k(const float* __restrict__ rpb, unsigned short* __restrict__ BM){
  int w = blockIdx.x / 6, h = blockIdx.x - (blockIdx.x/6)*6;
  int t = threadIdx.x;
  unsigned short* o = BM + ((size_t)blockIdx.x << 12);
  int wh = w >> 3, ww = w & 7;
  for (int z = 0; z < 16; ++z){
    int idx = t*16 + z;                 // 0..4095
    int i = idx >> 6, j = idx & 63;
    float val = -30000.0f;
    if (i < 49 && j < 49){
      int yi = i/7, xi = i - (i/7)*7, yj = j/7, xj = j - (j/7)*7;
      int pi_ = wh*7 + yi, qi_ = ww*7 + xi;
      int pj_ = wh*7 + yj, qj_ = ww*7 + xj;
      int li = (pi_<49?0:(pi_<53?1:2))*3 + (qi_<49?0:(qi_<53?1:2));
      int lj = (pj_<49?0:(pj_<53?1:2))*3 + (qj_<49?0:(qj_<53?1:2));
      int rel = (yi-yj+6)*13 + (xi-xj+6);
      val = rpb[rel*6 + h] + ((li == lj) ? 0.0f : -100.0f);
    }
    o[idx] = f2u(val);
  }
}

// ---------------- MFMA GEMM: block = 8 waves, 128 rows x (NCG*192) cols ----------
// K chunked at 32 with PREFETCH DOUBLE-BUFFER: issue global_load_lds for chunk c+1
// into buf^1 BEFORE computing chunk c from buf -> one __syncthreads per chunk and
// staging latency hides under the 12-MFMA compute phase. 16B granules swizzled
// (sw32, both sides) -> conflict-free ds_read_b128.
// LN kernels (LNMODE!=0): As full-K 49.2 KB (LN needs whole rows) + Ws dbuf 24.6
//   = 73.7 KB, 2 blk/CU. LNMODE=0: As dbuf + Ws dbuf = 41 KB -> 3 blk/CU (24 w/CU).
// EPI 0: +bias, scale cols<192 (QKV) -> bf16   1: +bias, scatter + res=x -> f32
//     2: +bias, fast GELU -> bf16               3: +bias, res=out -> f32
template<int KTOT, int NCG, int LNMODE, int EPI>
__global__ __launch_bounds__(512, LNMODE ? 4 : 6) void gemm_kernel(
    const void* __restrict__ A, int astride, long row0g,
    const unsigned short* __restrict__ Wt,     // [nW][KTOT] bf16
    const float* __restrict__ lng, const float* __restrict__ lnb,
    const float* __restrict__ bias, const float* __restrict__ res,
    void* __restrict__ outp, int ostride, const int* __restrict__ rowmap){
  constexpr bool AFULL = (LNMODE != 0);       // full-K As only for LN kernels
  constexpr int NCH = KTOT / 32;              // K chunks of 32 per col-group
  __shared__ __align__(16) unsigned short As[AFULL ? 128*192 : 2*128*32];
  __shared__ __align__(16) unsigned short Ws[2*192*32];
  int tid = threadIdx.x;
  // XCD-bijective swizzle (m204): contiguous chunk of virtual (by,bx) per XCD.
  int gx = gridDim.x;
  int nwg = gx * gridDim.y;
  int orig = blockIdx.y * gx + blockIdx.x;     // HW dispatch order (x fastest)
  int qc = nwg >> 3, rc = nwg & 7;
  int xcd = orig & 7, idxk = orig >> 3;
  int wgid = (xcd < rc ? xcd*(qc+1) : rc*(qc+1) + (xcd-rc)*qc) + idxk;
  int bx = wgid % gx, by = wgid / gx;
  long lrow0 = (long)by * 128;                 // local (slab) row base
  int lane = tid & 63, wv = tid >> 6;
  int rw = wv >> 2, cw = wv & 3;               // row-wave (0..1), col-wave (0..3)
  int quad = lane >> 4, l16 = lane & 15;

  // ---- staging issue helpers (gload_lds: linear LDS dest, swizzled source) ----
  auto stage_w = [&](int gg, int cc, int h){   // 192 rows x 64B = 12 wave-issues
    int n0s = (bx*NCG + gg) * 192;
    unsigned short* dst = Ws + h*(192*32);
    {
      int gi = wv*64 + lane;
      int r = gi >> 2, g = gi & 3;
      GLD16(Wt + (long)(n0s + r)*KTOT + cc*32 + (sw32(r,g)<<3), dst + (wv<<9));
    }
    if (wv < 4){
      int idx = 8 + wv;
      int gi = idx*64 + lane;
      int r = gi >> 2, g = gi & 3;
      GLD16(Wt + (long)(n0s + r)*KTOT + cc*32 + (sw32(r,g)<<3), dst + (idx<<9));
    }
  };
  auto stage_a = [&](int cc, int h){           // 128 rows x 64B = 8 wave-issues
    unsigned short* dst = As + h*(128*32);
    int gi = wv*64 + lane;
    int r = gi >> 2, g = gi & 3;
    GLD16((const unsigned short*)A + (lrow0 + r)*(long)astride + cc*32 + (sw32(r,g)<<3),
          dst + (wv<<9));
  };

  if constexpr (LNMODE != 0){
    // single-pass LN staging into full-K As (24-granule rows, slot = g ^ (r&7))
    int rr = tid >> 2, sub = tid & 3;          // 128 rows x 4 segments of 48
    long srow = (LNMODE == 1) ? (long)rowmap[row0g + lrow0 + rr] : (row0g + lrow0 + rr);
    const float* rp = (const float*)A + srow*192 + sub*48;
    float va[48];
    float s = 0.f, q2 = 0.f;
    #pragma unroll
    for (int i = 0; i < 12; ++i){
      float4 f = *(const float4*)(rp + i*4);
      va[i*4+0] = f.x; va[i*4+1] = f.y; va[i*4+2] = f.z; va[i*4+3] = f.w;
      s += (f.x + f.y) + (f.z + f.w);
      q2 = fmaf(f.x, f.x, q2); q2 = fmaf(f.y, f.y, q2);
      q2 = fmaf(f.z, f.z, q2); q2 = fmaf(f.w, f.w, q2);
    }
    s  += __shfl_xor(s, 1);  q2 += __shfl_xor(q2, 1);
    s  += __shfl_xor(s, 2);  q2 += __shfl_xor(q2, 2);
    float mean = s*(1.f/192.f);
    float rs = rsqrtf(q2*(1.f/192.f) - mean*mean + 1e-5f);
    float mrs = mean * rs;
    unsigned short* dstb = As + rr*192;
    #pragma unroll
    for (int i = 0; i < 12; ++i){
      float4 g4 = *(const float4*)(lng + sub*48 + i*4);
      float4 b4 = *(const float4*)(lnb + sub*48 + i*4);
      ushort4 o;
      o.x = f2u(fmaf(fmaf(va[i*4+0], rs, -mrs), g4.x, b4.x));
      o.y = f2u(fmaf(fmaf(va[i*4+1], rs, -mrs), g4.y, b4.y));
      o.z = f2u(fmaf(fmaf(va[i*4+2], rs, -mrs), g4.z, b4.z));
      o.w = f2u(fmaf(fmaf(va[i*4+3], rs, -mrs), g4.w, b4.w));
      *(ushort4*)(dstb + (((sub*6 + (i>>1)) ^ (rr&7))<<3) + ((i&1)<<2)) = o;
    }
  } else {
    stage_a(0, 0);
  }
  stage_w(0, 0, 0);
  __syncthreads();                             // LN writes + chunk0 staged

  int cur = 0;
  #pragma unroll
  for (int g = 0; g < NCG; ++g){
    int n0 = (bx*NCG + g) * 192;
    floatx4 acc[12];
    #pragma unroll
    for (int i = 0; i < 12; ++i) acc[i] = (floatx4){0.f,0.f,0.f,0.f};

    for (int c = 0; c < NCH; ++c){
      // prefetch next chunk into the other half (disjoint from current reads)
      int cn = c + 1, gn = g;
      if (cn == NCH){ cn = 0; gn = g + 1; }
      if (gn < NCG){
        if constexpr (!AFULL) stage_a(cn, cur ^ 1);
        stage_w(gn, cn, cur ^ 1);
      }
      // compute chunk c
      short8 af[4];
      if constexpr (AFULL){
        #pragma unroll
        for (int m = 0; m < 4; ++m){
          int r = rw*64 + m*16 + l16;
          af[m] = *(const short8*)(As + r*192 + (((c*4 + quad) ^ (r&7))<<3));
        }
      } else {
        const unsigned short* Ac = As + cur*(128*32);
        #pragma unroll
        for (int m = 0; m < 4; ++m){
          int r = rw*64 + m*16 + l16;
          af[m] = *(const short8*)(Ac + r*32 + (sw32(r,quad)<<3));
        }
      }
      const unsigned short* Wc = Ws + cur*(192*32);
      #pragma unroll
      for (int n = 0; n < 3; ++n){
        int rb = cw*48 + n*16 + l16;
        short8 bf = *(const short8*)(Wc + rb*32 + (sw32(rb,quad)<<3));
        #pragma unroll
        for (int m = 0; m < 4; ++m)
          acc[m*3+n] = __builtin_amdgcn_mfma_f32_16x16x32_bf16(af[m], bf, acc[m*3+n], 0, 0, 0);
      }
      __syncthreads();                         // next chunk landed; reads done
      cur ^= 1;
    }

    // epilogue: D row = quad*4+reg, col = lane&15 (verified gfx950 C/D mapping)
    #pragma unroll
    for (int m = 0; m < 4; ++m){
      #pragma unroll
      for (int r2 = 0; r2 < 4; ++r2){
        long lm = lrow0 + rw*64 + m*16 + quad*4 + r2;
        long drow = 0;
        if (EPI == 1) drow = rowmap[row0g + lm];
        if (EPI == 3) drow = row0g + lm;
        #pragma unroll
        for (int n = 0; n < 3; ++n){
          int col = n0 + cw*48 + n*16 + l16;
          float v = acc[m*3+n][r2] + bias[col];
          if (EPI == 0){
            if (col < 192) v *= SCALE_Q;
            ((unsigned short*)outp)[lm*(long)ostride + col] = f2u(v);
          } else if (EPI == 1){
            v += res[drow*192 + col];
            ((float*)outp)[drow*192 + col] = v;
          } else if (EPI == 2){
            // tanh-form GELU via exp2: v * sigmoid(1.59577*v*(1+0.044715*v^2))
            float z2 = -2.3022082f * v * fmaf(v*v, 0.044715f, 1.0f);
            v = v * __builtin_amdgcn_rcpf(1.0f + exp2f(z2));
            ((unsigned short*)outp)[lm*(long)ostride + col] = f2u(v);
          } else {
            v += res[drow*192 + col];
            ((float*)outp)[drow*192 + col] = v;
          }
        }
      }
    }
  }
}

// ---------------- MFMA window attention: one wave per (window, head) ----------------
// (verified in round 4)
__global__ __launch_bounds__(64) void attn_kernel(unsigned short* __restrict__ qkv,
    const unsigned short* __restrict__ BM, long win0g){
  __shared__ __align__(16) unsigned short Vt[32*64];   // V^T [d][j], swizzled
  __shared__ __align__(16) unsigned short Pl[64*72];   // P [i][j], pad 72
  int bid = blockIdx.x;
  int wb = bid / 6, head = bid - wb*6;
  int t = threadIdx.x;
  int q = t >> 4, l16 = t & 15;
  long base = (long)wb * 49 * 576;
  const unsigned short* qkvb = qkv + base;

  // zero Vt cols j=48..63 (j=48 rewritten below; same-wave DS ops ordered)
  #pragma unroll
  for (int z = 0; z < 8; ++z){
    int idx = t + z*64;
    int d = idx >> 4, jz = 48 + (idx & 15);
    Vt[d*64 + ((((jz>>3) ^ (d&7))<<3) | (jz&7))] = 0;
  }
  // stage V^T (transpose on LDS write)
  for (int idx = t; idx < 784; idx += 64){
    int j = idx >> 4, d2 = (idx & 15)*2;
    unsigned int u = *(const unsigned int*)(qkvb + (long)j*576 + 384 + head*32 + d2);
    Vt[d2*64 + ((((j>>3) ^ (d2&7))<<3) | (j&7))]       = (unsigned short)(u & 0xffffu);
    Vt[(d2+1)*64 + ((((j>>3) ^ ((d2+1)&7))<<3) | (j&7))] = (unsigned short)(u >> 16);
  }

  // ---- S^T = K·Q^T ----
  short8 kf[4], qf[4];
  #pragma unroll
  for (int jt = 0; jt < 4; ++jt){
    int j = jt*16 + l16; j = j > 48 ? 48 : j;
    kf[jt] = *(const short8*)(qkvb + (long)j*576 + 192 + head*32 + q*8);
  }
  #pragma unroll
  for (int it = 0; it < 4; ++it){
    int i = it*16 + l16; i = i > 48 ? 48 : i;
    qf[it] = *(const short8*)(qkvb + (long)i*576 + head*32 + q*8);
  }
  floatx4 acc[16];
  #pragma unroll
  for (int z = 0; z < 16; ++z) acc[z] = (floatx4){0.f,0.f,0.f,0.f};
  #pragma unroll
  for (int jt = 0; jt < 4; ++jt){
    #pragma unroll
    for (int it = 0; it < 4; ++it)
      acc[jt*4+it] = __builtin_amdgcn_mfma_f32_16x16x32_bf16(kf[jt], qf[it], acc[jt*4+it], 0, 0, 0);
  }

  // ---- bias+mask, softmax over j, scale by 1/sum, pack P to LDS ----
  int w = (int)((win0g + wb) & 63);
  const unsigned short* bmp = BM + ((size_t)(w*6 + head) << 12);
  #pragma unroll
  for (int it = 0; it < 4; ++it){
    float mx = -3.0e38f;
    #pragma unroll
    for (int jt = 0; jt < 4; ++jt){
      ushort4 bm = *(const ushort4*)(bmp + (it*16 + l16)*64 + jt*16 + q*4);
      floatx4 s = acc[jt*4+it];
      s[0] += u2f(bm.x); s[1] += u2f(bm.y); s[2] += u2f(bm.z); s[3] += u2f(bm.w);
      acc[jt*4+it] = s;
      mx = fmaxf(mx, fmaxf(fmaxf(s[0], s[1]), fmaxf(s[2], s[3])));
    }
    mx = fmaxf(mx, __shfl_xor(mx, 16));
    mx = fmaxf(mx, __shfl_xor(mx, 32));
    float sum = 0.f;
    #pragma unroll
    for (int jt = 0; jt < 4; ++jt){
      floatx4 s = acc[jt*4+it];
      s[0] = __expf(s[0]-mx); s[1] = __expf(s[1]-mx);
      s[2] = __expf(s[2]-mx); s[3] = __expf(s[3]-mx);
      acc[jt*4+it] = s;
      sum += (s[0]+s[1]) + (s[2]+s[3]);
    }
    sum += __shfl_xor(sum, 16);
    sum += __shfl_xor(sum, 32);
    float inv = 1.0f / sum;
    #pragma unroll
    for (int jt = 0; jt < 4; ++jt){
      floatx4 s = acc[jt*4+it];
      ushort4 pk;
      pk.x = f2u(s[0]*inv); pk.y = f2u(s[1]*inv);
      pk.z = f2u(s[2]*inv); pk.w = f2u(s[3]*inv);
      *(ushort4*)(Pl + (it*16 + l16)*72 + jt*16 + q*4) = pk;
    }
  }
  __syncthreads();

  // ---- O = P·V ----
  floatx4 oa[8];
  #pragma unroll
  for (int z = 0; z < 8; ++z) oa[z] = (floatx4){0.f,0.f,0.f,0.f};
  #pragma unroll
  for (int ks = 0; ks < 2; ++ks){
    short8 pf[4];
    #pragma unroll
    for (int mt = 0; mt < 4; ++mt)
      pf[mt] = *(const short8*)(Pl + (mt*16 + l16)*72 + ks*32 + q*8);
    #pragma unroll
    for (int nt = 0; nt < 2; ++nt){
      int d = nt*16 + l16;
      short8 vf = *(const short8*)(Vt + d*64 + (((ks*4 + q) ^ (d&7))<<3));
      #pragma unroll
      for (int mt = 0; mt < 4; ++mt)
        oa[mt*2+nt] = __builtin_amdgcn_mfma_f32_16x16x32_bf16(pf[mt], vf, oa[mt*2+nt], 0, 0, 0);
    }
  }
  // write O over own q-slice (block-local, race-free)
  #pragma unroll
  for (int mt = 0; mt < 4; ++mt){
    #pragma unroll
    for (int r = 0; r < 4; ++r){
      int i = mt*16 + q*4 + r;
      if (i < 49){
        unsigned short* op = qkv + base + (long)i*576 + head*32;
        op[l16]      = f2u(oa[mt*2+0][r]);
        op[16 + l16] = f2u(oa[mt*2+1][r]);
      }
    }
  }
}

extern "C" void kernel_launch(void* const* d_in, const int* in_sizes, int n_in,
                              void* d_out, int out_size, void* d_ws, size_t ws_size,
                              hipStream_t stream){
  const float* x     = (const float*)d_in[0];
  const float* ln1_g = (const float*)d_in[1];
  const float* ln1_b = (const float*)d_in[2];
  const float* qkv_w = (const float*)d_in[3];
  const float* qkv_b = (const float*)d_in[4];
  const float* proj_w= (const float*)d_in[5];
  const float* proj_b= (const float*)d_in[6];
  const float* rpb   = (const float*)d_in[7];
  const float* ln2_g = (const float*)d_in[8];
  const float* ln2_b = (const float*)d_in[9];
  const float* w1    = (const float*)d_in[10];
  const float* b1    = (const float*)d_in[11];
  const float* w2    = (const float*)d_in[12];
  const float* b2    = (const float*)d_in[13];
  float* out = (float*)d_out;

  // ws layout: bf16 transposed weights | rowmap | BM table | activation scratch
  unsigned short* wt_qkv  = (unsigned short*)d_ws;        // 576 x 192
  unsigned short* wt_proj = wt_qkv  + 576*192;            // 192 x 192
  unsigned short* wt_m1   = wt_proj + 192*192;            // 768 x 192
  unsigned short* wt_m2   = wt_m1   + 768*192;            // 192 x 768
  int* rowmap = (int*)(wt_m2 + 192*768);                  // M_TOT ints
  unsigned short* bm = (unsigned short*)(rowmap + M_TOT); // 384 x 4096 bf16
  unsigned short* buf = bm + (size_t)384*4096;
  size_t ovh = (size_t)(576*192 + 192*192 + 768*192 + 192*768)*2 + (size_t)M_TOT*4
             + (size_t)384*4096*2;
  size_t bufb = ws_size > ovh ? ws_size - ovh : 0;

  // --- slab sizing: multiples of 128 rows (gy = rows/128) ---
  int da = 64;
  while (da > 2 && (size_t)3136*(size_t)da*1152ULL > bufb) da >>= 1;
  long Sa = 3136L*da;             // attention slab rows (whole images, da even)
  int nA = 64/da;
  static const long smlist[] = {200704,100352,50176,25088,12544,6272,1792,1024,512,256,128};
  long Sm = 128;
  for (int i = 0; i < 11; ++i) if ((size_t)smlist[i]*1536ULL <= bufb){ Sm = smlist[i]; break; }
  int nM = (int)(M_TOT / Sm);

  // ---- prep: weights -> bf16 transposed; row gather map; bias+mask table ----
  conv_wt<<<(192*576+255)/256, 256, 0, stream>>>(qkv_w, wt_qkv, 192, 576);
  conv_wt<<<(192*192+255)/256, 256, 0, stream>>>(proj_w, wt_proj, 192, 192);
  conv_wt<<<(192*768+255)/256, 256, 0, stream>>>(w1, wt_m1, 192, 768);
  conv_wt<<<(768*192+255)/256, 256, 0, stream>>>(w2, wt_m2, 768, 192);
  rowmap_k<<<(M_TOT+255)/256, 256, 0, stream>>>(rowmap);
  bm_k<<<384, 256, 0, stream>>>(rpb, bm);

  // ---- attention branch: x -> out (= x + attn(ln1(x))) ----
  for (int s = 0; s < nA; ++s){
    long r0 = (long)s*Sa;
    gemm_kernel<192,3,1,0><<<dim3(1, Sa/128), 512, 0, stream>>>(
        x, 192, r0, wt_qkv, ln1_g, ln1_b, qkv_b, nullptr, buf, 576, rowmap);
    attn_kernel<<<(int)(Sa/49)*6, 64, 0, stream>>>(buf, bm, r0/49);
    gemm_kernel<192,1,0,1><<<dim3(1, Sa/128), 512, 0, stream>>>(
        buf, 576, r0, wt_proj, nullptr, nullptr, proj_b, x, out, 192, rowmap);
  }

  // ---- MLP branch: out -> out (= x2 + mlp(ln2(x2))) ----
  for (int s = 0; s < nM; ++s){
    long r0 = (long)s*Sm;
    gemm_kernel<192,2,2,2><<<dim3(2, Sm/128), 512, 0, stream>>>(
        out, 192, r0, wt_m1, ln2_g, ln2_b, b1, nullptr, buf, 768, rowmap);
    gemm_kernel<768,1,0,3><<<dim3(1, Sm/128), 512, 0, stream>>>(
        buf, 768, r0, wt_m2, nullptr, nullptr, b2, out, out, 192, rowmap);
  }
}